// Round 9
// baseline (9589.535 us; speedup 1.0000x reference)
//
#include <hip/hip_runtime.h>
#include <math.h>

// Problem constants
#define Gd   896
#define Bd   32
#define Td   1024
#define Cd   128
#define HDd  896
#define NWG  112          // 56 col-groups (16 cols) x 2 batch-halves (16 batches)
#define SPIN_MAX 4194304  // bounded spin (single-line poll): terminates instead of hanging

typedef short  short8 __attribute__((ext_vector_type(8)));
typedef float  f32x4  __attribute__((ext_vector_type(4)));
typedef unsigned short us4 __attribute__((ext_vector_type(4)));

__device__ __forceinline__ unsigned short f2bf(float f){
  unsigned u = __float_as_uint(f);
  u = u + 0x7FFFu + ((u >> 16) & 1u);      // RNE
  return (unsigned short)(u >> 16);
}
__device__ __forceinline__ float bf2f(unsigned short h){
  return __uint_as_float(((unsigned)h) << 16);
}
__device__ __forceinline__ f32x4 mfma16(short8 a, short8 b, f32x4 c){
  return __builtin_amdgcn_mfma_f32_16x16x32_bf16(a, b, c, 0, 0, 0);
}

// ---- Agent-scope relaxed atomics: lower to plain global ops with sc bits,
// vmcnt-tracked, pipeline like normal loads. (R2-proven path.)
__device__ __forceinline__ unsigned long long ald8u(const unsigned short* p){
  return __hip_atomic_load((const unsigned long long*)p, __ATOMIC_RELAXED, __HIP_MEMORY_SCOPE_AGENT);
}
__device__ __forceinline__ short8 ald16(const unsigned short* p){
  union { unsigned long long u[2]; short8 s; } r;
  r.u[0] = __hip_atomic_load((const unsigned long long*)p,       __ATOMIC_RELAXED, __HIP_MEMORY_SCOPE_AGENT);
  r.u[1] = __hip_atomic_load((const unsigned long long*)(p + 4), __ATOMIC_RELAXED, __HIP_MEMORY_SCOPE_AGENT);
  return r.s;
}
__device__ __forceinline__ void ast8(unsigned short* p, us4 v){
  union { us4 s; unsigned long long u; } r; r.s = v;
  __hip_atomic_store((unsigned long long*)p, r.u, __ATOMIC_RELAXED, __HIP_MEMORY_SCOPE_AGENT);
}

// ---------------------------------------------------------------------------
// Init: x (fp32) -> hi/lo bf16 planes, h0 -> hi/lo bf16 planes, zero ctrl.
// ---------------------------------------------------------------------------
__global__ void init_k(const float* __restrict__ x, const float* __restrict__ st,
                       unsigned short* __restrict__ xhi, unsigned short* __restrict__ xlo,
                       unsigned short* __restrict__ h0hi, unsigned short* __restrict__ h0lo,
                       int* __restrict__ ctrl)
{
  const long long tid  = (long long)blockIdx.x * blockDim.x + threadIdx.x;
  const long long nthr = (long long)gridDim.x * blockDim.x;
  const long long NX4 = (long long)Bd * Td * Cd / 4;   // 1,048,576
  for (long long i = tid; i < NX4; i += nthr){
    f32x4 v = *(const f32x4*)(x + 4*i);
    us4 oh, ol;
    #pragma unroll
    for (int j = 0; j < 4; j++){
      unsigned short h = f2bf(v[j]);
      oh[j] = h; ol[j] = f2bf(v[j] - bf2f(h));
    }
    *(us4*)(xhi + 4*i) = oh;
    *(us4*)(xlo + 4*i) = ol;
  }
  const long long NH4 = (long long)Bd * Gd / 4;        // 7168
  for (long long i = tid; i < NH4; i += nthr){
    f32x4 v = *(const f32x4*)(st + 4*i);
    us4 oh, ol;
    #pragma unroll
    for (int j = 0; j < 4; j++){
      unsigned short h = f2bf(v[j]);
      oh[j] = h; ol[j] = f2bf(v[j] - bf2f(h));
    }
    *(us4*)(h0hi + 4*i) = oh;
    *(us4*)(h0lo + 4*i) = ol;
  }
  if (tid < 512) ctrl[tid] = 0;   // ctrl[0]=epoch par0, ctrl[16]=epoch par1
}

// ---------------------------------------------------------------------------
// Persistent GRU scan kernel. 112 WGs x 256 threads, 1 WG/CU.
// R8 base (single-line epoch barrier, 5.63ms) + early per-khi-wave signal:
//  - each khi wave drains ITS OWN stores (h only at that point) and lane0
//    atomicAdds the PARITY epoch; out/hlast HBM stores are issued AFTER the
//    signal and drain overlapped with the next step's poll (they fall to the
//    compiler's vmcnt(0) at the next s_barrier).
//  - end-of-step __syncthreads (B4) deleted: LDS reuse hazards are ordered
//    by B1(t+1)+B2(t+1)/B3 (all waves pass B1 before any staging write; a
//    WG's signal implies it passed B3, i.e. finished its staging reads).
//  - parity-split epochs (64B apart): consumers wait only on their own
//    batch-half's producers; target = 112*t (56 WGs x 2 khi waves).
// ---------------------------------------------------------------------------
__global__ __launch_bounds__(256, 1)
void gru_persistent(const float* __restrict__ w_ih, const float* __restrict__ w_hh,
                    const float* __restrict__ b_ih, const float* __restrict__ b_hh,
                    const float* __restrict__ w_post, const float* __restrict__ b_post,
                    const unsigned short* __restrict__ xhi, const unsigned short* __restrict__ xlo,
                    unsigned short* __restrict__ h0hi, unsigned short* __restrict__ h0lo,
                    unsigned short* __restrict__ h1hi, unsigned short* __restrict__ h1lo,
                    int* __restrict__ ctrl, float* __restrict__ out, float* __restrict__ hlast)
{
  const int wg   = blockIdx.x;
  const int tid  = threadIdx.x;
  const int w    = tid >> 6;            // wave 0..3
  const int lane = tid & 63;
  const int q    = lane >> 4;           // k-chunk (operands) / row-quad (acc)
  const int c    = lane & 15;           // A row m / B col n / acc col
  const int cg   = wg >> 1;             // column group (16 cols)
  const int b0   = (wg & 1) * 16;       // batch half base
  const int cw   = w & 1;               // column half within group
  const bool khi = (w >> 1) != 0;
  const int gw   = cg * 16 + cw * 8;    // this wave's 8-column base
  const int b    = b0 + c;              // this lane's batch column
  const int par  = wg & 1;              // batch parity

  int* ep = ctrl + par * 16;            // parity epoch (own 64B line)

  // LDS: staged h slice [16 batches][896+pad] hi+lo (pitch 904 ~conflict-free)
  __shared__ unsigned short sh_hi[16 * 904];          // 28,928 B
  __shared__ unsigned short sh_lo[16 * 904];          // 28,928 B
  __shared__ float lred[2][64][8];                    //  4,096 B (indexed by cw)

  // ---- Load weight fragments into registers (hi/lo bf16). wf[kt][tile][hl] ----
  short8 wf[16][2][2];
  #pragma unroll
  for (int kt = 0; kt < 16; kt++){
    const bool isx = khi && (kt >= 12);
    const int kb = khi ? (kt < 12 ? 512 + kt*32 : (kt - 12)*32) : kt*32;
    #pragma unroll
    for (int tile = 0; tile < 2; tile++){
      const float* src = nullptr; long long rowoff = 0; bool zero = false;
      if (!isx){
        if (tile == 0){ int row = (c < 8) ? (gw + c) : (Gd + gw + c - 8);
                        src = w_hh; rowoff = (long long)row * Gd; }
        else { if (c < 8){ int row = 2*Gd + gw + c; src = w_hh; rowoff = (long long)row * Gd; }
               else      { int row = gw + c - 8;    src = w_post; rowoff = (long long)row * Gd; } }
      } else {
        if (tile == 0){ int row = (c < 8) ? (gw + c) : (Gd + gw + c - 8);
                        src = w_ih; rowoff = (long long)row * Cd; }
        else { if (c < 8){ int row = 2*Gd + gw + c; src = w_ih; rowoff = (long long)row * Cd; }
               else zero = true; }
      }
      short8 shi, slo;
      #pragma unroll
      for (int j = 0; j < 8; j++){
        float v = zero ? 0.f : src[rowoff + kb + q*8 + j];
        unsigned short h = f2bf(v);
        unsigned short l = f2bf(v - bf2f(h));
        shi[j] = (short)h; slo[j] = (short)l;
      }
      wf[kt][tile][0] = shi; wf[kt][tile][1] = slo;
    }
  }

  // ---- Per-lane biases for the combine (indexed by acc row = 4q+i) ----
  float brz[4], bA[4], bB[4];
  #pragma unroll
  for (int i = 0; i < 4; i++){
    int row = 4*q + i;
    if (q < 2){ int idx = gw + row;  brz[i] = b_ih[idx] + b_hh[idx];
                int nr = 2*Gd + gw + row; bA[i] = b_ih[nr]; bB[i] = b_hh[nr]; }
    else      { int idx = Gd + gw + row - 8; brz[i] = b_ih[idx] + b_hh[idx];
                bA[i] = b_post[gw + row - 8]; bB[i] = 0.f; }
  }

  unsigned short* hhi_[2] = { h0hi, h1hi };
  unsigned short* hlo_[2] = { h0lo, h1lo };
  const f32x4 zero4 = {0.f, 0.f, 0.f, 0.f};

  for (int t = 0; t < Td; t++){
    // ---- grid barrier: single-line parity-epoch poll (one lane only) ----
    if (t > 0){
      if (tid == 0){
        const int tgt = NWG * t;        // 56 WGs x 2 khi-wave signals per step
        for (int spin = 0; spin < SPIN_MAX; spin++){
          int e = __hip_atomic_load(ep, __ATOMIC_RELAXED, __HIP_MEMORY_SCOPE_AGENT);
          if (e >= tgt) break;
          __builtin_amdgcn_s_sleep(1);
        }
      }
      __syncthreads();                                   // B1
    }

    const unsigned short* phi = hhi_[t & 1];
    const unsigned short* plo = hlo_[t & 1];
    unsigned short* nhi = hhi_[(t + 1) & 1];
    unsigned short* nlo = hlo_[(t + 1) & 1];

    // ---- Stage this WG's h slice [b0..b0+16) x [0..896) into LDS ----
    // Lane-contiguous 8B loads; LDS writes row-linear (conflict-free, R2).
    {
      const unsigned short* s_h = phi + (long long)b0 * Gd;
      const unsigned short* s_l = plo + (long long)b0 * Gd;
      unsigned long long vh[14], vl[14];
      #pragma unroll
      for (int j = 0; j < 14; j++){
        const int e8 = tid + j * 256;                    // u64 index 0..3583
        vh[j] = ald8u(s_h + e8 * 4);
        vl[j] = ald8u(s_l + e8 * 4);
      }
      #pragma unroll
      for (int j = 0; j < 14; j++){
        const int e8 = tid + j * 256;
        const int bl = e8 / 224;                         // batch row 0..15
        const int kk = (e8 - bl * 224) * 4;              // k offset 0..892
        *(unsigned long long*)(&sh_hi[bl * 904 + kk]) = vh[j];
        *(unsigned long long*)(&sh_lo[bl * 904 + kk]) = vl[j];
      }
    }
    __syncthreads();                                     // B2: slice visible

    // ---- B fragments from LDS (+ x plain loads for khi waves) ----
    short8 bh[16], bl_[16];
    if (!khi){
      #pragma unroll
      for (int kt = 0; kt < 16; kt++){
        bh[kt]  = *(const short8*)(&sh_hi[c * 904 + kt*32 + q*8]);
        bl_[kt] = *(const short8*)(&sh_lo[c * 904 + kt*32 + q*8]);
      }
    } else {
      #pragma unroll
      for (int kt = 0; kt < 12; kt++){
        bh[kt]  = *(const short8*)(&sh_hi[c * 904 + 512 + kt*32 + q*8]);
        bl_[kt] = *(const short8*)(&sh_lo[c * 904 + 512 + kt*32 + q*8]);
      }
      const long long xoff = ((long long)b * Td + t) * Cd;
      #pragma unroll
      for (int kt = 12; kt < 16; kt++){  // x: plain loads, L2-cached
        bh[kt]  = *(const short8*)(xhi + xoff + (kt - 12)*32 + q*8);
        bl_[kt] = *(const short8*)(xlo + xoff + (kt - 12)*32 + q*8);
      }
    }
    us4 hpH, hpL;                        // h_prev slice for the update (khi, q<2)
    if (khi && q < 2){
      hpH = *(const us4*)(&sh_hi[c * 904 + gw + 4*q]);
      hpL = *(const us4*)(&sh_lo[c * 904 + gw + 4*q]);
    }

    // ---- MFMA K-loop: main + two correction chains per tile ----
    f32x4 a0m = zero4, a0c = zero4, a0d = zero4;
    f32x4 a1m = zero4, a1c = zero4, a1d = zero4;
    f32x4 axm = zero4, axc = zero4, axd = zero4;
    #pragma unroll
    for (int kt = 0; kt < 16; kt++){
      const bool isx = khi && (kt >= 12);
      const short8 w0h = wf[kt][0][0], w0l = wf[kt][0][1];
      const short8 w1h = wf[kt][1][0], w1l = wf[kt][1][1];
      a0m = mfma16(w0h, bh[kt], a0m);
      a0c = mfma16(w0h, bl_[kt], a0c);
      a0d = mfma16(w0l, bh[kt], a0d);
      if (!isx){
        a1m = mfma16(w1h, bh[kt], a1m);
        a1c = mfma16(w1h, bl_[kt], a1c);
        a1d = mfma16(w1l, bh[kt], a1d);
      } else {
        axm = mfma16(w1h, bh[kt], axm);
        axc = mfma16(w1h, bl_[kt], axc);
        axd = mfma16(w1l, bh[kt], axd);
      }
    }

    f32x4 sT0 = (a0m + a0c) + a0d;
    f32x4 sT1 = (a1m + a1c) + a1d;
    if (!khi){
      #pragma unroll
      for (int i = 0; i < 4; i++){ lred[cw][lane][i] = sT0[i]; lred[cw][lane][4+i] = sT1[i]; }
    }
    __syncthreads();                                     // B3

    if (khi){
      #pragma unroll
      for (int i = 0; i < 4; i++){ sT0[i] += lred[cw][lane][i]; sT1[i] += lred[cw][lane][4+i]; }
      f32x4 sX = (axm + axc) + axd;

      // sigmoid of T0 rows: q<2 -> r values, q>=2 -> z values
      float sv[4];
      #pragma unroll
      for (int i = 0; i < 4; i++) sv[i] = 1.f / (1.f + __expf(-(sT0[i] + brz[i])));
      float zv[4];
      #pragma unroll
      for (int i = 0; i < 4; i++) zv[i] = __shfl_down(sv[i], 32);

      f32x4 hf;
      if (q < 2){
        us4 sh, sl;
        #pragma unroll
        for (int i = 0; i < 4; i++){
          float hp = bf2f(hpH[i]) + bf2f(hpL[i]);
          float n  = tanhf((sX[i] + bA[i]) + sv[i] * (sT1[i] + bB[i]));
          float hv = (1.f - zv[i]) * n + zv[i] * hp;
          hf[i] = hv;
          unsigned short hh = f2bf(hv);
          sh[i] = hh; sl[i] = f2bf(hv - bf2f(hh));
        }
        ast8(nhi + (long long)b * Gd + gw + 4*q, sh);   // publish h gen t+1
        ast8(nlo + (long long)b * Gd + gw + 4*q, sl);
      }
      // Drain THIS wave's stores (h only at this point); signal parity epoch.
      // out/hlast issued AFTER — drain overlapped with next step's poll.
      __builtin_amdgcn_s_waitcnt(0);
      if (lane == 0)
        __hip_atomic_fetch_add(ep, 1, __ATOMIC_RELAXED, __HIP_MEMORY_SCOPE_AGENT);
      if (q >= 2 && t > 0){
        f32x4 o;
        #pragma unroll
        for (int i = 0; i < 4; i++){ float v = sT1[i] + bA[i]; o[i] = v > 0.f ? v : 0.f; }
        *(f32x4*)(out + ((long long)b * Td + (t - 1)) * HDd + gw + 4*(q - 2)) = o;
      }
      if (q < 2 && t == Td - 1)
        *(f32x4*)(hlast + (long long)b * Gd + gw + 4*q) = hf;
    }
    // no end-of-step barrier: B1/B2/B3 of the next iteration order LDS reuse
  }

  // ---- Epilogue: out[:, T-1, :] = relu(w_post . h_T + b) ----
  if (tid == 0){
    const int tgt = NWG * Td;
    for (int spin = 0; spin < SPIN_MAX; spin++){
      int e = __hip_atomic_load(ep, __ATOMIC_RELAXED, __HIP_MEMORY_SCOPE_AGENT);
      if (e >= tgt) break;
      __builtin_amdgcn_s_sleep(1);
    }
  }
  __syncthreads();

  const unsigned short* fhi = hhi_[Td & 1] + (long long)b * Gd;   // = h0 planes
  const unsigned short* flo = hlo_[Td & 1] + (long long)b * Gd;
  f32x4 apm = zero4, apc = zero4, apd = zero4;
  const int nkt = khi ? 12 : 16;
  #pragma unroll
  for (int kt = 0; kt < 16; kt++){
    if (kt < nkt){
      const int off = khi ? (512 + kt*32 + q*8) : (kt*32 + q*8);
      short8 vh = ald16(fhi + off);
      short8 vl = ald16(flo + off);
      apm = mfma16(wf[kt][1][0], vh, apm);
      apc = mfma16(wf[kt][1][0], vl, apc);
      apd = mfma16(wf[kt][1][1], vh, apd);
    }
  }
  f32x4 sP = (apm + apc) + apd;
  if (!khi){
    #pragma unroll
    for (int i = 0; i < 4; i++) lred[cw][lane][i] = sP[i];
  }
  __syncthreads();
  if (khi && q >= 2){
    #pragma unroll
    for (int i = 0; i < 4; i++) sP[i] += lred[cw][lane][i];
    f32x4 o;
    #pragma unroll
    for (int i = 0; i < 4; i++){ float v = sP[i] + bA[i]; o[i] = v > 0.f ? v : 0.f; }
    *(f32x4*)(out + ((long long)b * Td + (Td - 1)) * HDd + gw + 4*(q - 2)) = o;
  }
}

// ---------------------------------------------------------------------------
extern "C" void kernel_launch(void* const* d_in, const int* in_sizes, int n_in,
                              void* d_out, int out_size, void* d_ws, size_t ws_size,
                              hipStream_t stream)
{
  const float* x      = (const float*)d_in[0];
  const float* state  = (const float*)d_in[1];
  const float* w_ih   = (const float*)d_in[2];
  const float* w_hh   = (const float*)d_in[3];
  const float* b_ih   = (const float*)d_in[4];
  const float* b_hh   = (const float*)d_in[5];
  const float* w_post = (const float*)d_in[6];
  const float* b_post = (const float*)d_in[7];

  float* out   = (float*)d_out;
  float* hlast = out + (long long)Bd * Td * HDd;

  // workspace layout (~17.0 MB)
  char* ws = (char*)d_ws;
  unsigned short* xhi  = (unsigned short*)ws;                      //  8,388,608 B
  unsigned short* xlo  = (unsigned short*)(ws +  8388608);         //  8,388,608 B
  unsigned short* h0hi = (unsigned short*)(ws + 16777216);         //     57,344 B
  unsigned short* h0lo = (unsigned short*)(ws + 16834560);         //     57,344 B
  unsigned short* h1hi = (unsigned short*)(ws + 16891904);         //     57,344 B
  unsigned short* h1lo = (unsigned short*)(ws + 16949248);         //     57,344 B
  int*            ctrl = (int*)(ws + 17006592);                    //      2,048 B

  hipLaunchKernelGGL(init_k, dim3(2048), dim3(256), 0, stream,
                     x, state, xhi, xlo, h0hi, h0lo, ctrl);

  hipLaunchKernelGGL(gru_persistent, dim3(NWG), dim3(256), 0, stream,
                     w_ih, w_hh, b_ih, b_hh, w_post, b_post, xhi, xlo,
                     h0hi, h0lo, h1hi, h1lo, ctrl, out, hlast);
}

// Round 11
// 6315.148 us; speedup vs baseline: 1.5185x; 1.5185x over previous
//
#include <hip/hip_runtime.h>
#include <math.h>

// Problem constants
#define Gd   896
#define Bd   32
#define Td   1024
#define Cd   128
#define HDd  896
#define NWG  112          // 56 col-groups (16 cols) x 2 batch-halves (16 batches)
#define SPIN_MAX 4194304  // bounded spin (single-line poll): terminates instead of hanging

typedef short  short8 __attribute__((ext_vector_type(8)));
typedef float  f32x4  __attribute__((ext_vector_type(4)));
typedef unsigned short us4 __attribute__((ext_vector_type(4)));

__device__ __forceinline__ unsigned short f2bf(float f){
  unsigned u = __float_as_uint(f);
  u = u + 0x7FFFu + ((u >> 16) & 1u);      // RNE
  return (unsigned short)(u >> 16);
}
__device__ __forceinline__ float bf2f(unsigned short h){
  return __uint_as_float(((unsigned)h) << 16);
}
__device__ __forceinline__ f32x4 mfma16(short8 a, short8 b, f32x4 c){
  return __builtin_amdgcn_mfma_f32_16x16x32_bf16(a, b, c, 0, 0, 0);
}

// ---- Agent-scope relaxed atomics: lower to plain global ops with sc bits,
// vmcnt-tracked, pipeline like normal loads. (R2-proven path.)
__device__ __forceinline__ unsigned long long ald8u(const unsigned short* p){
  return __hip_atomic_load((const unsigned long long*)p, __ATOMIC_RELAXED, __HIP_MEMORY_SCOPE_AGENT);
}
__device__ __forceinline__ short8 ald16(const unsigned short* p){
  union { unsigned long long u[2]; short8 s; } r;
  r.u[0] = __hip_atomic_load((const unsigned long long*)p,       __ATOMIC_RELAXED, __HIP_MEMORY_SCOPE_AGENT);
  r.u[1] = __hip_atomic_load((const unsigned long long*)(p + 4), __ATOMIC_RELAXED, __HIP_MEMORY_SCOPE_AGENT);
  return r.s;
}
__device__ __forceinline__ void ast8(unsigned short* p, us4 v){
  union { us4 s; unsigned long long u; } r; r.s = v;
  __hip_atomic_store((unsigned long long*)p, r.u, __ATOMIC_RELAXED, __HIP_MEMORY_SCOPE_AGENT);
}

// ---------------------------------------------------------------------------
// Init: x (fp32) -> hi/lo bf16 planes, h0 -> hi/lo bf16 planes, zero ctrl.
// ---------------------------------------------------------------------------
__global__ void init_k(const float* __restrict__ x, const float* __restrict__ st,
                       unsigned short* __restrict__ xhi, unsigned short* __restrict__ xlo,
                       unsigned short* __restrict__ h0hi, unsigned short* __restrict__ h0lo,
                       int* __restrict__ ctrl)
{
  const long long tid  = (long long)blockIdx.x * blockDim.x + threadIdx.x;
  const long long nthr = (long long)gridDim.x * blockDim.x;
  const long long NX4 = (long long)Bd * Td * Cd / 4;   // 1,048,576
  for (long long i = tid; i < NX4; i += nthr){
    f32x4 v = *(const f32x4*)(x + 4*i);
    us4 oh, ol;
    #pragma unroll
    for (int j = 0; j < 4; j++){
      unsigned short h = f2bf(v[j]);
      oh[j] = h; ol[j] = f2bf(v[j] - bf2f(h));
    }
    *(us4*)(xhi + 4*i) = oh;
    *(us4*)(xlo + 4*i) = ol;
  }
  const long long NH4 = (long long)Bd * Gd / 4;        // 7168
  for (long long i = tid; i < NH4; i += nthr){
    f32x4 v = *(const f32x4*)(st + 4*i);
    us4 oh, ol;
    #pragma unroll
    for (int j = 0; j < 4; j++){
      unsigned short h = f2bf(v[j]);
      oh[j] = h; ol[j] = f2bf(v[j] - bf2f(h));
    }
    *(us4*)(h0hi + 4*i) = oh;
    *(us4*)(h0lo + 4*i) = ol;
  }
  if (tid < 512) ctrl[tid] = 0;        // ctrl[0] = epoch counter
}

// ---------------------------------------------------------------------------
// Persistent GRU scan kernel. 112 WGs x 256 threads, 1 WG/CU.
// R8 base (single-line epoch barrier, 5.63ms). ONE change at end-of-step:
//   h publish -> drain (h acks ONLY) -> issue out/hlast (left outstanding)
//   -> RAW s_barrier (no implicit vmcnt drain) -> tid0 epoch signal.
// This keeps R8's exact ordering guarantee (signal only after WG converged
// AND h LLC-visible) but removes the out-store HBM ack (~1us) from the
// global critical path; out stores drain at the NEXT step's B1 syncthreads,
// overlapped with the poll window (local cost only).
// ---------------------------------------------------------------------------
__global__ __launch_bounds__(256, 1)
void gru_persistent(const float* __restrict__ w_ih, const float* __restrict__ w_hh,
                    const float* __restrict__ b_ih, const float* __restrict__ b_hh,
                    const float* __restrict__ w_post, const float* __restrict__ b_post,
                    const unsigned short* __restrict__ xhi, const unsigned short* __restrict__ xlo,
                    unsigned short* __restrict__ h0hi, unsigned short* __restrict__ h0lo,
                    unsigned short* __restrict__ h1hi, unsigned short* __restrict__ h1lo,
                    int* __restrict__ ctrl, float* __restrict__ out, float* __restrict__ hlast)
{
  const int wg   = blockIdx.x;
  const int tid  = threadIdx.x;
  const int w    = tid >> 6;            // wave 0..3
  const int lane = tid & 63;
  const int q    = lane >> 4;           // k-chunk (operands) / row-quad (acc)
  const int c    = lane & 15;           // A row m / B col n / acc col
  const int cg   = wg >> 1;             // column group (16 cols)
  const int b0   = (wg & 1) * 16;       // batch half base
  const int cw   = w & 1;               // column half within group
  const bool khi = (w >> 1) != 0;
  const int gw   = cg * 16 + cw * 8;    // this wave's 8-column base
  const int b    = b0 + c;              // this lane's batch column

  int* epoch = ctrl;                    // single aggregate step counter

  // LDS: staged h slice [16 batches][896+pad] hi+lo (pitch 904 ~conflict-free)
  __shared__ unsigned short sh_hi[16 * 904];          // 28,928 B
  __shared__ unsigned short sh_lo[16 * 904];          // 28,928 B
  __shared__ float lred[2][64][8];                    //  4,096 B (indexed by cw)

  // ---- Load weight fragments into registers (hi/lo bf16). wf[kt][tile][hl] ----
  short8 wf[16][2][2];
  #pragma unroll
  for (int kt = 0; kt < 16; kt++){
    const bool isx = khi && (kt >= 12);
    const int kb = khi ? (kt < 12 ? 512 + kt*32 : (kt - 12)*32) : kt*32;
    #pragma unroll
    for (int tile = 0; tile < 2; tile++){
      const float* src = nullptr; long long rowoff = 0; bool zero = false;
      if (!isx){
        if (tile == 0){ int row = (c < 8) ? (gw + c) : (Gd + gw + c - 8);
                        src = w_hh; rowoff = (long long)row * Gd; }
        else { if (c < 8){ int row = 2*Gd + gw + c; src = w_hh; rowoff = (long long)row * Gd; }
               else      { int row = gw + c - 8;    src = w_post; rowoff = (long long)row * Gd; } }
      } else {
        if (tile == 0){ int row = (c < 8) ? (gw + c) : (Gd + gw + c - 8);
                        src = w_ih; rowoff = (long long)row * Cd; }
        else { if (c < 8){ int row = 2*Gd + gw + c; src = w_ih; rowoff = (long long)row * Cd; }
               else zero = true; }
      }
      short8 shi, slo;
      #pragma unroll
      for (int j = 0; j < 8; j++){
        float v = zero ? 0.f : src[rowoff + kb + q*8 + j];
        unsigned short h = f2bf(v);
        unsigned short l = f2bf(v - bf2f(h));
        shi[j] = (short)h; slo[j] = (short)l;
      }
      wf[kt][tile][0] = shi; wf[kt][tile][1] = slo;
    }
  }

  // ---- Per-lane biases for the combine (indexed by acc row = 4q+i) ----
  float brz[4], bA[4], bB[4];
  #pragma unroll
  for (int i = 0; i < 4; i++){
    int row = 4*q + i;
    if (q < 2){ int idx = gw + row;  brz[i] = b_ih[idx] + b_hh[idx];
                int nr = 2*Gd + gw + row; bA[i] = b_ih[nr]; bB[i] = b_hh[nr]; }
    else      { int idx = Gd + gw + row - 8; brz[i] = b_ih[idx] + b_hh[idx];
                bA[i] = b_post[gw + row - 8]; bB[i] = 0.f; }
  }

  unsigned short* hhi_[2] = { h0hi, h1hi };
  unsigned short* hlo_[2] = { h0lo, h1lo };
  const f32x4 zero4 = {0.f, 0.f, 0.f, 0.f};

  for (int t = 0; t < Td; t++){
    // ---- grid barrier: single-line epoch poll (one lane only) ----
    if (t > 0){
      if (tid == 0){
        const int tgt = NWG * t;
        for (int spin = 0; spin < SPIN_MAX; spin++){
          int e = __hip_atomic_load(epoch, __ATOMIC_RELAXED, __HIP_MEMORY_SCOPE_AGENT);
          if (e >= tgt) break;
          __builtin_amdgcn_s_sleep(1);
        }
      }
      __syncthreads();                                   // B1 (drains prev out stores, overlapped w/ poll)
    }

    const unsigned short* phi = hhi_[t & 1];
    const unsigned short* plo = hlo_[t & 1];
    unsigned short* nhi = hhi_[(t + 1) & 1];
    unsigned short* nlo = hlo_[(t + 1) & 1];

    // ---- Stage this WG's h slice [b0..b0+16) x [0..896) into LDS ----
    // Lane-contiguous 8B loads; LDS writes row-linear (conflict-free, R2).
    {
      const unsigned short* s_h = phi + (long long)b0 * Gd;
      const unsigned short* s_l = plo + (long long)b0 * Gd;
      unsigned long long vh[14], vl[14];
      #pragma unroll
      for (int j = 0; j < 14; j++){
        const int e8 = tid + j * 256;                    // u64 index 0..3583
        vh[j] = ald8u(s_h + e8 * 4);
        vl[j] = ald8u(s_l + e8 * 4);
      }
      #pragma unroll
      for (int j = 0; j < 14; j++){
        const int e8 = tid + j * 256;
        const int bl = e8 / 224;                         // batch row 0..15
        const int kk = (e8 - bl * 224) * 4;              // k offset 0..892
        *(unsigned long long*)(&sh_hi[bl * 904 + kk]) = vh[j];
        *(unsigned long long*)(&sh_lo[bl * 904 + kk]) = vl[j];
      }
    }
    __syncthreads();                                     // B2: slice visible

    // ---- B fragments from LDS (+ x plain loads for khi waves) ----
    short8 bh[16], bl_[16];
    if (!khi){
      #pragma unroll
      for (int kt = 0; kt < 16; kt++){
        bh[kt]  = *(const short8*)(&sh_hi[c * 904 + kt*32 + q*8]);
        bl_[kt] = *(const short8*)(&sh_lo[c * 904 + kt*32 + q*8]);
      }
    } else {
      #pragma unroll
      for (int kt = 0; kt < 12; kt++){
        bh[kt]  = *(const short8*)(&sh_hi[c * 904 + 512 + kt*32 + q*8]);
        bl_[kt] = *(const short8*)(&sh_lo[c * 904 + 512 + kt*32 + q*8]);
      }
      const long long xoff = ((long long)b * Td + t) * Cd;
      #pragma unroll
      for (int kt = 12; kt < 16; kt++){  // x: plain loads, L2-cached
        bh[kt]  = *(const short8*)(xhi + xoff + (kt - 12)*32 + q*8);
        bl_[kt] = *(const short8*)(xlo + xoff + (kt - 12)*32 + q*8);
      }
    }
    us4 hpH, hpL;                        // h_prev slice for the update (khi, q<2)
    if (khi && q < 2){
      hpH = *(const us4*)(&sh_hi[c * 904 + gw + 4*q]);
      hpL = *(const us4*)(&sh_lo[c * 904 + gw + 4*q]);
    }

    // ---- MFMA K-loop: main + two correction chains per tile ----
    f32x4 a0m = zero4, a0c = zero4, a0d = zero4;
    f32x4 a1m = zero4, a1c = zero4, a1d = zero4;
    f32x4 axm = zero4, axc = zero4, axd = zero4;
    #pragma unroll
    for (int kt = 0; kt < 16; kt++){
      const bool isx = khi && (kt >= 12);
      const short8 w0h = wf[kt][0][0], w0l = wf[kt][0][1];
      const short8 w1h = wf[kt][1][0], w1l = wf[kt][1][1];
      a0m = mfma16(w0h, bh[kt], a0m);
      a0c = mfma16(w0h, bl_[kt], a0c);
      a0d = mfma16(w0l, bh[kt], a0d);
      if (!isx){
        a1m = mfma16(w1h, bh[kt], a1m);
        a1c = mfma16(w1h, bl_[kt], a1c);
        a1d = mfma16(w1l, bh[kt], a1d);
      } else {
        axm = mfma16(w1h, bh[kt], axm);
        axc = mfma16(w1h, bl_[kt], axc);
        axd = mfma16(w1l, bh[kt], axd);
      }
    }

    f32x4 sT0 = (a0m + a0c) + a0d;
    f32x4 sT1 = (a1m + a1c) + a1d;
    if (!khi){
      #pragma unroll
      for (int i = 0; i < 4; i++){ lred[cw][lane][i] = sT0[i]; lred[cw][lane][4+i] = sT1[i]; }
    }
    __syncthreads();                                     // B3

    f32x4 hf, ov;                        // khi results held for post-drain store
    if (khi){
      #pragma unroll
      for (int i = 0; i < 4; i++){ sT0[i] += lred[cw][lane][i]; sT1[i] += lred[cw][lane][4+i]; }
      f32x4 sX = (axm + axc) + axd;

      // sigmoid of T0 rows: q<2 -> r values, q>=2 -> z values
      float sv[4];
      #pragma unroll
      for (int i = 0; i < 4; i++) sv[i] = 1.f / (1.f + __expf(-(sT0[i] + brz[i])));
      float zv[4];
      #pragma unroll
      for (int i = 0; i < 4; i++) zv[i] = __shfl_down(sv[i], 32);

      if (q < 2){
        us4 sh, sl;
        #pragma unroll
        for (int i = 0; i < 4; i++){
          float hp = bf2f(hpH[i]) + bf2f(hpL[i]);
          float n  = tanhf((sX[i] + bA[i]) + sv[i] * (sT1[i] + bB[i]));
          float hv = (1.f - zv[i]) * n + zv[i] * hp;
          hf[i] = hv;
          unsigned short hh = f2bf(hv);
          sh[i] = hh; sl[i] = f2bf(hv - bf2f(hh));
        }
        ast8(nhi + (long long)b * Gd + gw + 4*q, sh);   // publish h gen t+1
        ast8(nlo + (long long)b * Gd + gw + 4*q, sl);
      } else {
        #pragma unroll
        for (int i = 0; i < 4; i++){ float v = sT1[i] + bA[i]; ov[i] = v > 0.f ? v : 0.f; }
      }
    }

    // ---- End-of-step: drain h acks ONLY, then issue out/hlast, then raw
    // barrier (no implicit vmcnt drain), then single epoch signal. ----
    __builtin_amdgcn_sched_barrier(0);
    __builtin_amdgcn_s_waitcnt(0);       // khi q<2: h store acks; others: trivial
    __builtin_amdgcn_sched_barrier(0);
    if (khi){
      if (q >= 2 && t > 0)
        *(f32x4*)(out + ((long long)b * Td + (t - 1)) * HDd + gw + 4*(q - 2)) = ov;
      if (q < 2 && t == Td - 1)
        *(f32x4*)(hlast + (long long)b * Gd + gw + 4*q) = hf;
    }
    __builtin_amdgcn_sched_barrier(0);
    __builtin_amdgcn_s_barrier();        // B4 raw: converge WITHOUT draining out stores
    __builtin_amdgcn_sched_barrier(0);
    if (tid == 0)
      __hip_atomic_fetch_add(epoch, 1, __ATOMIC_RELAXED, __HIP_MEMORY_SCOPE_AGENT);
  }

  // ---- Epilogue: out[:, T-1, :] = relu(w_post . h_T + b) ----
  if (tid == 0){
    const int tgt = NWG * Td;
    for (int spin = 0; spin < SPIN_MAX; spin++){
      int e = __hip_atomic_load(epoch, __ATOMIC_RELAXED, __HIP_MEMORY_SCOPE_AGENT);
      if (e >= tgt) break;
      __builtin_amdgcn_s_sleep(1);
    }
  }
  __syncthreads();

  const unsigned short* fhi = hhi_[Td & 1] + (long long)b * Gd;   // = h0 planes
  const unsigned short* flo = hlo_[Td & 1] + (long long)b * Gd;
  f32x4 apm = zero4, apc = zero4, apd = zero4;
  const int nkt = khi ? 12 : 16;
  #pragma unroll
  for (int kt = 0; kt < 16; kt++){
    if (kt < nkt){
      const int off = khi ? (512 + kt*32 + q*8) : (kt*32 + q*8);
      short8 vh = ald16(fhi + off);
      short8 vl = ald16(flo + off);
      apm = mfma16(wf[kt][1][0], vh, apm);
      apc = mfma16(wf[kt][1][0], vl, apc);
      apd = mfma16(wf[kt][1][1], vh, apd);
    }
  }
  f32x4 sP = (apm + apc) + apd;
  if (!khi){
    #pragma unroll
    for (int i = 0; i < 4; i++) lred[cw][lane][i] = sP[i];
  }
  __syncthreads();
  if (khi && q >= 2){
    #pragma unroll
    for (int i = 0; i < 4; i++) sP[i] += lred[cw][lane][i];
    f32x4 o;
    #pragma unroll
    for (int i = 0; i < 4; i++){ float v = sP[i] + bA[i]; o[i] = v > 0.f ? v : 0.f; }
    *(f32x4*)(out + ((long long)b * Td + (Td - 1)) * HDd + gw + 4*(q - 2)) = o;
  }
}

// ---------------------------------------------------------------------------
extern "C" void kernel_launch(void* const* d_in, const int* in_sizes, int n_in,
                              void* d_out, int out_size, void* d_ws, size_t ws_size,
                              hipStream_t stream)
{
  const float* x      = (const float*)d_in[0];
  const float* state  = (const float*)d_in[1];
  const float* w_ih   = (const float*)d_in[2];
  const float* w_hh   = (const float*)d_in[3];
  const float* b_ih   = (const float*)d_in[4];
  const float* b_hh   = (const float*)d_in[5];
  const float* w_post = (const float*)d_in[6];
  const float* b_post = (const float*)d_in[7];

  float* out   = (float*)d_out;
  float* hlast = out + (long long)Bd * Td * HDd;

  // workspace layout (~17.0 MB)
  char* ws = (char*)d_ws;
  unsigned short* xhi  = (unsigned short*)ws;                      //  8,388,608 B
  unsigned short* xlo  = (unsigned short*)(ws +  8388608);         //  8,388,608 B
  unsigned short* h0hi = (unsigned short*)(ws + 16777216);         //     57,344 B
  unsigned short* h0lo = (unsigned short*)(ws + 16834560);         //     57,344 B
  unsigned short* h1hi = (unsigned short*)(ws + 16891904);         //     57,344 B
  unsigned short* h1lo = (unsigned short*)(ws + 16949248);         //     57,344 B
  int*            ctrl = (int*)(ws + 17006592);                    //      2,048 B

  hipLaunchKernelGGL(init_k, dim3(2048), dim3(256), 0, stream,
                     x, state, xhi, xlo, h0hi, h0lo, ctrl);

  hipLaunchKernelGGL(gru_persistent, dim3(NWG), dim3(256), 0, stream,
                     w_ih, w_hh, b_ih, b_hh, w_post, b_post, xhi, xlo,
                     h0hi, h0lo, h1hi, h1lo, ctrl, out, hlast);
}

// Round 12
// 5705.430 us; speedup vs baseline: 1.6808x; 1.1069x over previous
//
#include <hip/hip_runtime.h>
#include <math.h>

// Problem constants
#define Gd   896
#define Bd   32
#define Td   1024
#define Cd   128
#define HDd  896
#define NWG  112          // 56 col-groups (16 cols) x 2 batch-halves (16 batches)
#define SPIN_MAX 4194304  // bounded spin (single-line poll): terminates instead of hanging

typedef short  short8 __attribute__((ext_vector_type(8)));
typedef float  f32x4  __attribute__((ext_vector_type(4)));
typedef unsigned short us4 __attribute__((ext_vector_type(4)));

__device__ __forceinline__ unsigned short f2bf(float f){
  unsigned u = __float_as_uint(f);
  u = u + 0x7FFFu + ((u >> 16) & 1u);      // RNE
  return (unsigned short)(u >> 16);
}
__device__ __forceinline__ float bf2f(unsigned short h){
  return __uint_as_float(((unsigned)h) << 16);
}
__device__ __forceinline__ f32x4 mfma16(short8 a, short8 b, f32x4 c){
  return __builtin_amdgcn_mfma_f32_16x16x32_bf16(a, b, c, 0, 0, 0);
}

// ---- Agent-scope relaxed atomics: lower to plain global ops with sc bits,
// vmcnt-tracked, pipeline like normal loads. (R2-proven path.)
__device__ __forceinline__ unsigned long long ald8u(const unsigned short* p){
  return __hip_atomic_load((const unsigned long long*)p, __ATOMIC_RELAXED, __HIP_MEMORY_SCOPE_AGENT);
}
__device__ __forceinline__ short8 ald16(const unsigned short* p){
  union { unsigned long long u[2]; short8 s; } r;
  r.u[0] = __hip_atomic_load((const unsigned long long*)p,       __ATOMIC_RELAXED, __HIP_MEMORY_SCOPE_AGENT);
  r.u[1] = __hip_atomic_load((const unsigned long long*)(p + 4), __ATOMIC_RELAXED, __HIP_MEMORY_SCOPE_AGENT);
  return r.s;
}
__device__ __forceinline__ void ast8(unsigned short* p, us4 v){
  union { us4 s; unsigned long long u; } r; r.s = v;
  __hip_atomic_store((unsigned long long*)p, r.u, __ATOMIC_RELAXED, __HIP_MEMORY_SCOPE_AGENT);
}
__device__ __forceinline__ int eld(const int* p){
  return __hip_atomic_load(p, __ATOMIC_RELAXED, __HIP_MEMORY_SCOPE_AGENT);
}

// Pipelined single-line poll: keep 4 epoch reads in flight, check the oldest
// (issued ~4 slots earlier -> already returned), refill. Read period -> ~RT/4,
// detect latency ~RT+RT/4 instead of ~1.5RT with blocking read+sleep.
__device__ __forceinline__ void poll_epoch(const int* epoch, int tgt){
  int e0 = eld(epoch), e1 = eld(epoch), e2 = eld(epoch), e3 = eld(epoch);
  for (int spin = 0; spin < SPIN_MAX; spin++){
    if (e0 >= tgt) break;  e0 = eld(epoch);
    if (e1 >= tgt) break;  e1 = eld(epoch);
    if (e2 >= tgt) break;  e2 = eld(epoch);
    if (e3 >= tgt) break;  e3 = eld(epoch);
  }
}

// ---------------------------------------------------------------------------
// Init: x (fp32) -> hi/lo bf16 planes, h0 -> hi/lo bf16 planes, zero ctrl.
// ---------------------------------------------------------------------------
__global__ void init_k(const float* __restrict__ x, const float* __restrict__ st,
                       unsigned short* __restrict__ xhi, unsigned short* __restrict__ xlo,
                       unsigned short* __restrict__ h0hi, unsigned short* __restrict__ h0lo,
                       int* __restrict__ ctrl)
{
  const long long tid  = (long long)blockIdx.x * blockDim.x + threadIdx.x;
  const long long nthr = (long long)gridDim.x * blockDim.x;
  const long long NX4 = (long long)Bd * Td * Cd / 4;   // 1,048,576
  for (long long i = tid; i < NX4; i += nthr){
    f32x4 v = *(const f32x4*)(x + 4*i);
    us4 oh, ol;
    #pragma unroll
    for (int j = 0; j < 4; j++){
      unsigned short h = f2bf(v[j]);
      oh[j] = h; ol[j] = f2bf(v[j] - bf2f(h));
    }
    *(us4*)(xhi + 4*i) = oh;
    *(us4*)(xlo + 4*i) = ol;
  }
  const long long NH4 = (long long)Bd * Gd / 4;        // 7168
  for (long long i = tid; i < NH4; i += nthr){
    f32x4 v = *(const f32x4*)(st + 4*i);
    us4 oh, ol;
    #pragma unroll
    for (int j = 0; j < 4; j++){
      unsigned short h = f2bf(v[j]);
      oh[j] = h; ol[j] = f2bf(v[j] - bf2f(h));
    }
    *(us4*)(h0hi + 4*i) = oh;
    *(us4*)(h0lo + 4*i) = ol;
  }
  if (tid < 512) ctrl[tid] = 0;        // ctrl[0] = epoch counter
}

// ---------------------------------------------------------------------------
// Persistent GRU scan kernel. 112 WGs x 256 threads, 1 WG/CU.
// R8 structure exactly (proven 5.63ms): single-line epoch barrier, end-of-step
// __syncthreads (B4, drains all stores) + tid0 signal. ONE change: the poll
// is software-pipelined 4-deep (consumer-side only; detect latency ~RT+RT/4
// instead of ~1.5RT). R6/R9/R11 all showed producer-side signal reordering
// regresses — that area is closed.
// ---------------------------------------------------------------------------
__global__ __launch_bounds__(256, 1)
void gru_persistent(const float* __restrict__ w_ih, const float* __restrict__ w_hh,
                    const float* __restrict__ b_ih, const float* __restrict__ b_hh,
                    const float* __restrict__ w_post, const float* __restrict__ b_post,
                    const unsigned short* __restrict__ xhi, const unsigned short* __restrict__ xlo,
                    unsigned short* __restrict__ h0hi, unsigned short* __restrict__ h0lo,
                    unsigned short* __restrict__ h1hi, unsigned short* __restrict__ h1lo,
                    int* __restrict__ ctrl, float* __restrict__ out, float* __restrict__ hlast)
{
  const int wg   = blockIdx.x;
  const int tid  = threadIdx.x;
  const int w    = tid >> 6;            // wave 0..3
  const int lane = tid & 63;
  const int q    = lane >> 4;           // k-chunk (operands) / row-quad (acc)
  const int c    = lane & 15;           // A row m / B col n / acc col
  const int cg   = wg >> 1;             // column group (16 cols)
  const int b0   = (wg & 1) * 16;       // batch half base
  const int cw   = w & 1;               // column half within group
  const bool khi = (w >> 1) != 0;
  const int gw   = cg * 16 + cw * 8;    // this wave's 8-column base
  const int b    = b0 + c;              // this lane's batch column

  int* epoch = ctrl;                    // single aggregate step counter

  // LDS: staged h slice [16 batches][896+pad] hi+lo (pitch 904 ~conflict-free)
  __shared__ unsigned short sh_hi[16 * 904];          // 28,928 B
  __shared__ unsigned short sh_lo[16 * 904];          // 28,928 B
  __shared__ float lred[2][64][8];                    //  4,096 B (indexed by cw)

  // ---- Load weight fragments into registers (hi/lo bf16). wf[kt][tile][hl] ----
  short8 wf[16][2][2];
  #pragma unroll
  for (int kt = 0; kt < 16; kt++){
    const bool isx = khi && (kt >= 12);
    const int kb = khi ? (kt < 12 ? 512 + kt*32 : (kt - 12)*32) : kt*32;
    #pragma unroll
    for (int tile = 0; tile < 2; tile++){
      const float* src = nullptr; long long rowoff = 0; bool zero = false;
      if (!isx){
        if (tile == 0){ int row = (c < 8) ? (gw + c) : (Gd + gw + c - 8);
                        src = w_hh; rowoff = (long long)row * Gd; }
        else { if (c < 8){ int row = 2*Gd + gw + c; src = w_hh; rowoff = (long long)row * Gd; }
               else      { int row = gw + c - 8;    src = w_post; rowoff = (long long)row * Gd; } }
      } else {
        if (tile == 0){ int row = (c < 8) ? (gw + c) : (Gd + gw + c - 8);
                        src = w_ih; rowoff = (long long)row * Cd; }
        else { if (c < 8){ int row = 2*Gd + gw + c; src = w_ih; rowoff = (long long)row * Cd; }
               else zero = true; }
      }
      short8 shi, slo;
      #pragma unroll
      for (int j = 0; j < 8; j++){
        float v = zero ? 0.f : src[rowoff + kb + q*8 + j];
        unsigned short h = f2bf(v);
        unsigned short l = f2bf(v - bf2f(h));
        shi[j] = (short)h; slo[j] = (short)l;
      }
      wf[kt][tile][0] = shi; wf[kt][tile][1] = slo;
    }
  }

  // ---- Per-lane biases for the combine (indexed by acc row = 4q+i) ----
  float brz[4], bA[4], bB[4];
  #pragma unroll
  for (int i = 0; i < 4; i++){
    int row = 4*q + i;
    if (q < 2){ int idx = gw + row;  brz[i] = b_ih[idx] + b_hh[idx];
                int nr = 2*Gd + gw + row; bA[i] = b_ih[nr]; bB[i] = b_hh[nr]; }
    else      { int idx = Gd + gw + row - 8; brz[i] = b_ih[idx] + b_hh[idx];
                bA[i] = b_post[gw + row - 8]; bB[i] = 0.f; }
  }

  unsigned short* hhi_[2] = { h0hi, h1hi };
  unsigned short* hlo_[2] = { h0lo, h1lo };
  const f32x4 zero4 = {0.f, 0.f, 0.f, 0.f};

  for (int t = 0; t < Td; t++){
    // ---- grid barrier: pipelined single-line epoch poll (one lane only) ----
    if (t > 0){
      if (tid == 0) poll_epoch(epoch, NWG * t);
      __syncthreads();                                   // B1
    }

    const unsigned short* phi = hhi_[t & 1];
    const unsigned short* plo = hlo_[t & 1];
    unsigned short* nhi = hhi_[(t + 1) & 1];
    unsigned short* nlo = hlo_[(t + 1) & 1];

    // ---- Stage this WG's h slice [b0..b0+16) x [0..896) into LDS ----
    // Lane-contiguous 8B loads; LDS writes row-linear (conflict-free, R2).
    {
      const unsigned short* s_h = phi + (long long)b0 * Gd;
      const unsigned short* s_l = plo + (long long)b0 * Gd;
      unsigned long long vh[14], vl[14];
      #pragma unroll
      for (int j = 0; j < 14; j++){
        const int e8 = tid + j * 256;                    // u64 index 0..3583
        vh[j] = ald8u(s_h + e8 * 4);
        vl[j] = ald8u(s_l + e8 * 4);
      }
      #pragma unroll
      for (int j = 0; j < 14; j++){
        const int e8 = tid + j * 256;
        const int bl = e8 / 224;                         // batch row 0..15
        const int kk = (e8 - bl * 224) * 4;              // k offset 0..892
        *(unsigned long long*)(&sh_hi[bl * 904 + kk]) = vh[j];
        *(unsigned long long*)(&sh_lo[bl * 904 + kk]) = vl[j];
      }
    }
    __syncthreads();                                     // B2: slice visible

    // ---- B fragments from LDS (+ x plain loads for khi waves) ----
    short8 bh[16], bl_[16];
    if (!khi){
      #pragma unroll
      for (int kt = 0; kt < 16; kt++){
        bh[kt]  = *(const short8*)(&sh_hi[c * 904 + kt*32 + q*8]);
        bl_[kt] = *(const short8*)(&sh_lo[c * 904 + kt*32 + q*8]);
      }
    } else {
      #pragma unroll
      for (int kt = 0; kt < 12; kt++){
        bh[kt]  = *(const short8*)(&sh_hi[c * 904 + 512 + kt*32 + q*8]);
        bl_[kt] = *(const short8*)(&sh_lo[c * 904 + 512 + kt*32 + q*8]);
      }
      const long long xoff = ((long long)b * Td + t) * Cd;
      #pragma unroll
      for (int kt = 12; kt < 16; kt++){  // x: plain loads, L2-cached
        bh[kt]  = *(const short8*)(xhi + xoff + (kt - 12)*32 + q*8);
        bl_[kt] = *(const short8*)(xlo + xoff + (kt - 12)*32 + q*8);
      }
    }
    us4 hpH, hpL;                        // h_prev slice for the update (khi, q<2)
    if (khi && q < 2){
      hpH = *(const us4*)(&sh_hi[c * 904 + gw + 4*q]);
      hpL = *(const us4*)(&sh_lo[c * 904 + gw + 4*q]);
    }

    // ---- MFMA K-loop: main + two correction chains per tile ----
    f32x4 a0m = zero4, a0c = zero4, a0d = zero4;
    f32x4 a1m = zero4, a1c = zero4, a1d = zero4;
    f32x4 axm = zero4, axc = zero4, axd = zero4;
    #pragma unroll
    for (int kt = 0; kt < 16; kt++){
      const bool isx = khi && (kt >= 12);
      const short8 w0h = wf[kt][0][0], w0l = wf[kt][0][1];
      const short8 w1h = wf[kt][1][0], w1l = wf[kt][1][1];
      a0m = mfma16(w0h, bh[kt], a0m);
      a0c = mfma16(w0h, bl_[kt], a0c);
      a0d = mfma16(w0l, bh[kt], a0d);
      if (!isx){
        a1m = mfma16(w1h, bh[kt], a1m);
        a1c = mfma16(w1h, bl_[kt], a1c);
        a1d = mfma16(w1l, bh[kt], a1d);
      } else {
        axm = mfma16(w1h, bh[kt], axm);
        axc = mfma16(w1h, bl_[kt], axc);
        axd = mfma16(w1l, bh[kt], axd);
      }
    }

    f32x4 sT0 = (a0m + a0c) + a0d;
    f32x4 sT1 = (a1m + a1c) + a1d;
    if (!khi){
      #pragma unroll
      for (int i = 0; i < 4; i++){ lred[cw][lane][i] = sT0[i]; lred[cw][lane][4+i] = sT1[i]; }
    }
    __syncthreads();                                     // B3

    if (khi){
      #pragma unroll
      for (int i = 0; i < 4; i++){ sT0[i] += lred[cw][lane][i]; sT1[i] += lred[cw][lane][4+i]; }
      f32x4 sX = (axm + axc) + axd;

      // sigmoid of T0 rows: q<2 -> r values, q>=2 -> z values
      float sv[4];
      #pragma unroll
      for (int i = 0; i < 4; i++) sv[i] = 1.f / (1.f + __expf(-(sT0[i] + brz[i])));
      float zv[4];
      #pragma unroll
      for (int i = 0; i < 4; i++) zv[i] = __shfl_down(sv[i], 32);

      if (q < 2){
        us4 sh, sl; f32x4 hf;
        #pragma unroll
        for (int i = 0; i < 4; i++){
          float hp = bf2f(hpH[i]) + bf2f(hpL[i]);
          float n  = tanhf((sX[i] + bA[i]) + sv[i] * (sT1[i] + bB[i]));
          float hv = (1.f - zv[i]) * n + zv[i] * hp;
          hf[i] = hv;
          unsigned short hh = f2bf(hv);
          sh[i] = hh; sl[i] = f2bf(hv - bf2f(hh));
        }
        ast8(nhi + (long long)b * Gd + gw + 4*q, sh);   // publish h gen t+1
        ast8(nlo + (long long)b * Gd + gw + 4*q, sl);
        if (t == Td - 1)
          *(f32x4*)(hlast + (long long)b * Gd + gw + 4*q) = hf;
      } else {
        if (t > 0){
          f32x4 o;
          #pragma unroll
          for (int i = 0; i < 4; i++){ float v = sT1[i] + bA[i]; o[i] = v > 0.f ? v : 0.f; }
          *(f32x4*)(out + ((long long)b * Td + (t - 1)) * HDd + gw + 4*(q - 2)) = o;
        }
      }
    }
    // __syncthreads() drains each wave's vmcnt (h stores MALL-visible)
    __syncthreads();                                     // B4
    if (tid == 0){
      __builtin_amdgcn_s_waitcnt(0);     // belt & braces: own wave's stores drained
      __hip_atomic_fetch_add(epoch, 1, __ATOMIC_RELAXED, __HIP_MEMORY_SCOPE_AGENT);
    }
  }

  // ---- Epilogue: out[:, T-1, :] = relu(w_post . h_T + b) ----
  if (tid == 0) poll_epoch(epoch, NWG * Td);
  __syncthreads();

  const unsigned short* fhi = hhi_[Td & 1] + (long long)b * Gd;   // = h0 planes
  const unsigned short* flo = hlo_[Td & 1] + (long long)b * Gd;
  f32x4 apm = zero4, apc = zero4, apd = zero4;
  const int nkt = khi ? 12 : 16;
  #pragma unroll
  for (int kt = 0; kt < 16; kt++){
    if (kt < nkt){
      const int off = khi ? (512 + kt*32 + q*8) : (kt*32 + q*8);
      short8 vh = ald16(fhi + off);
      short8 vl = ald16(flo + off);
      apm = mfma16(wf[kt][1][0], vh, apm);
      apc = mfma16(wf[kt][1][0], vl, apc);
      apd = mfma16(wf[kt][1][1], vh, apd);
    }
  }
  f32x4 sP = (apm + apc) + apd;
  if (!khi){
    #pragma unroll
    for (int i = 0; i < 4; i++) lred[cw][lane][i] = sP[i];
  }
  __syncthreads();
  if (khi && q >= 2){
    #pragma unroll
    for (int i = 0; i < 4; i++) sP[i] += lred[cw][lane][i];
    f32x4 o;
    #pragma unroll
    for (int i = 0; i < 4; i++){ float v = sP[i] + bA[i]; o[i] = v > 0.f ? v : 0.f; }
    *(f32x4*)(out + ((long long)b * Td + (Td - 1)) * HDd + gw + 4*(q - 2)) = o;
  }
}

// ---------------------------------------------------------------------------
extern "C" void kernel_launch(void* const* d_in, const int* in_sizes, int n_in,
                              void* d_out, int out_size, void* d_ws, size_t ws_size,
                              hipStream_t stream)
{
  const float* x      = (const float*)d_in[0];
  const float* state  = (const float*)d_in[1];
  const float* w_ih   = (const float*)d_in[2];
  const float* w_hh   = (const float*)d_in[3];
  const float* b_ih   = (const float*)d_in[4];
  const float* b_hh   = (const float*)d_in[5];
  const float* w_post = (const float*)d_in[6];
  const float* b_post = (const float*)d_in[7];

  float* out   = (float*)d_out;
  float* hlast = out + (long long)Bd * Td * HDd;

  // workspace layout (~17.0 MB)
  char* ws = (char*)d_ws;
  unsigned short* xhi  = (unsigned short*)ws;                      //  8,388,608 B
  unsigned short* xlo  = (unsigned short*)(ws +  8388608);         //  8,388,608 B
  unsigned short* h0hi = (unsigned short*)(ws + 16777216);         //     57,344 B
  unsigned short* h0lo = (unsigned short*)(ws + 16834560);         //     57,344 B
  unsigned short* h1hi = (unsigned short*)(ws + 16891904);         //     57,344 B
  unsigned short* h1lo = (unsigned short*)(ws + 16949248);         //     57,344 B
  int*            ctrl = (int*)(ws + 17006592);                    //      2,048 B

  hipLaunchKernelGGL(init_k, dim3(2048), dim3(256), 0, stream,
                     x, state, xhi, xlo, h0hi, h0lo, ctrl);

  hipLaunchKernelGGL(gru_persistent, dim3(NWG), dim3(256), 0, stream,
                     w_ih, w_hh, b_ih, b_hh, w_post, b_post, xhi, xlo,
                     h0hi, h0lo, h1hi, h1lo, ctrl, out, hlast);
}

// Round 13
// 5135.011 us; speedup vs baseline: 1.8675x; 1.1111x over previous
//
#include <hip/hip_runtime.h>
#include <math.h>

// Problem constants
#define Gd   896
#define Bd   32
#define Td   1024
#define Cd   128
#define HDd  896
#define NWG  112          // 56 col-groups (16 cols) x 2 batch-halves (16 batches)
#define NPAR 56           // producers per parity (independent recurrences)
#define SPIN_MAX 4194304  // bounded spin (single-line poll): terminates instead of hanging

typedef short  short8 __attribute__((ext_vector_type(8)));
typedef float  f32x4  __attribute__((ext_vector_type(4)));
typedef unsigned short us4 __attribute__((ext_vector_type(4)));

__device__ __forceinline__ unsigned short f2bf(float f){
  unsigned u = __float_as_uint(f);
  u = u + 0x7FFFu + ((u >> 16) & 1u);      // RNE
  return (unsigned short)(u >> 16);
}
__device__ __forceinline__ float bf2f(unsigned short h){
  return __uint_as_float(((unsigned)h) << 16);
}
__device__ __forceinline__ f32x4 mfma16(short8 a, short8 b, f32x4 c){
  return __builtin_amdgcn_mfma_f32_16x16x32_bf16(a, b, c, 0, 0, 0);
}

// ---- Agent-scope relaxed atomics: lower to plain global ops with sc bits,
// vmcnt-tracked, pipeline like normal loads. (R2-proven path.)
__device__ __forceinline__ unsigned long long ald8u(const unsigned short* p){
  return __hip_atomic_load((const unsigned long long*)p, __ATOMIC_RELAXED, __HIP_MEMORY_SCOPE_AGENT);
}
__device__ __forceinline__ short8 ald16(const unsigned short* p){
  union { unsigned long long u[2]; short8 s; } r;
  r.u[0] = __hip_atomic_load((const unsigned long long*)p,       __ATOMIC_RELAXED, __HIP_MEMORY_SCOPE_AGENT);
  r.u[1] = __hip_atomic_load((const unsigned long long*)(p + 4), __ATOMIC_RELAXED, __HIP_MEMORY_SCOPE_AGENT);
  return r.s;
}
__device__ __forceinline__ void ast8(unsigned short* p, us4 v){
  union { us4 s; unsigned long long u; } r; r.s = v;
  __hip_atomic_store((unsigned long long*)p, r.u, __ATOMIC_RELAXED, __HIP_MEMORY_SCOPE_AGENT);
}
__device__ __forceinline__ int eld(const int* p){
  return __hip_atomic_load(p, __ATOMIC_RELAXED, __HIP_MEMORY_SCOPE_AGENT);
}

// Pipelined single-line poll (R12, neutral-but-harmless): keep 4 epoch reads
// in flight, check the oldest, refill.
__device__ __forceinline__ void poll_epoch(const int* epoch, int tgt){
  int e0 = eld(epoch), e1 = eld(epoch), e2 = eld(epoch), e3 = eld(epoch);
  for (int spin = 0; spin < SPIN_MAX; spin++){
    if (e0 >= tgt) break;  e0 = eld(epoch);
    if (e1 >= tgt) break;  e1 = eld(epoch);
    if (e2 >= tgt) break;  e2 = eld(epoch);
    if (e3 >= tgt) break;  e3 = eld(epoch);
  }
}

// ---------------------------------------------------------------------------
// Init: x (fp32) -> hi/lo bf16 planes, h0 -> hi/lo bf16 planes, zero ctrl.
// ---------------------------------------------------------------------------
__global__ void init_k(const float* __restrict__ x, const float* __restrict__ st,
                       unsigned short* __restrict__ xhi, unsigned short* __restrict__ xlo,
                       unsigned short* __restrict__ h0hi, unsigned short* __restrict__ h0lo,
                       int* __restrict__ ctrl)
{
  const long long tid  = (long long)blockIdx.x * blockDim.x + threadIdx.x;
  const long long nthr = (long long)gridDim.x * blockDim.x;
  const long long NX4 = (long long)Bd * Td * Cd / 4;   // 1,048,576
  for (long long i = tid; i < NX4; i += nthr){
    f32x4 v = *(const f32x4*)(x + 4*i);
    us4 oh, ol;
    #pragma unroll
    for (int j = 0; j < 4; j++){
      unsigned short h = f2bf(v[j]);
      oh[j] = h; ol[j] = f2bf(v[j] - bf2f(h));
    }
    *(us4*)(xhi + 4*i) = oh;
    *(us4*)(xlo + 4*i) = ol;
  }
  const long long NH4 = (long long)Bd * Gd / 4;        // 7168
  for (long long i = tid; i < NH4; i += nthr){
    f32x4 v = *(const f32x4*)(st + 4*i);
    us4 oh, ol;
    #pragma unroll
    for (int j = 0; j < 4; j++){
      unsigned short h = f2bf(v[j]);
      oh[j] = h; ol[j] = f2bf(v[j] - bf2f(h));
    }
    *(us4*)(h0hi + 4*i) = oh;
    *(us4*)(h0lo + 4*i) = ol;
  }
  if (tid < 512) ctrl[tid] = 0;   // ctrl[0]=epoch par0, ctrl[16]=epoch par1
}

// ---------------------------------------------------------------------------
// Persistent GRU scan kernel. 112 WGs x 256 threads, 1 WG/CU.
// R8/R12 structure exactly (proven 5.63ms): end-of-step __syncthreads (B4,
// drains all stores) + tid0 single signal. ONE change: PER-PARITY epoch
// counters (separate cache lines). The two batch halves are fully
// independent recurrences (disjoint h/out/hlast rows), so each WG waits
// only on the 56 producers it depends on — halving barrier fan-in and
// decoupling cross-parity skew. Unbounded parity drift is safe (disjoint
// state). R6/R9/R11: producer-side signal reordering is closed.
// ---------------------------------------------------------------------------
__global__ __launch_bounds__(256, 1)
void gru_persistent(const float* __restrict__ w_ih, const float* __restrict__ w_hh,
                    const float* __restrict__ b_ih, const float* __restrict__ b_hh,
                    const float* __restrict__ w_post, const float* __restrict__ b_post,
                    const unsigned short* __restrict__ xhi, const unsigned short* __restrict__ xlo,
                    unsigned short* __restrict__ h0hi, unsigned short* __restrict__ h0lo,
                    unsigned short* __restrict__ h1hi, unsigned short* __restrict__ h1lo,
                    int* __restrict__ ctrl, float* __restrict__ out, float* __restrict__ hlast)
{
  const int wg   = blockIdx.x;
  const int tid  = threadIdx.x;
  const int w    = tid >> 6;            // wave 0..3
  const int lane = tid & 63;
  const int q    = lane >> 4;           // k-chunk (operands) / row-quad (acc)
  const int c    = lane & 15;           // A row m / B col n / acc col
  const int cg   = wg >> 1;             // column group (16 cols)
  const int b0   = (wg & 1) * 16;       // batch half base
  const int cw   = w & 1;               // column half within group
  const bool khi = (w >> 1) != 0;
  const int gw   = cg * 16 + cw * 8;    // this wave's 8-column base
  const int b    = b0 + c;              // this lane's batch column

  int* epoch = ctrl + (wg & 1) * 16;    // per-parity step counter (own line)

  // LDS: staged h slice [16 batches][896+pad] hi+lo (pitch 904 ~conflict-free)
  __shared__ unsigned short sh_hi[16 * 904];          // 28,928 B
  __shared__ unsigned short sh_lo[16 * 904];          // 28,928 B
  __shared__ float lred[2][64][8];                    //  4,096 B (indexed by cw)

  // ---- Load weight fragments into registers (hi/lo bf16). wf[kt][tile][hl] ----
  short8 wf[16][2][2];
  #pragma unroll
  for (int kt = 0; kt < 16; kt++){
    const bool isx = khi && (kt >= 12);
    const int kb = khi ? (kt < 12 ? 512 + kt*32 : (kt - 12)*32) : kt*32;
    #pragma unroll
    for (int tile = 0; tile < 2; tile++){
      const float* src = nullptr; long long rowoff = 0; bool zero = false;
      if (!isx){
        if (tile == 0){ int row = (c < 8) ? (gw + c) : (Gd + gw + c - 8);
                        src = w_hh; rowoff = (long long)row * Gd; }
        else { if (c < 8){ int row = 2*Gd + gw + c; src = w_hh; rowoff = (long long)row * Gd; }
               else      { int row = gw + c - 8;    src = w_post; rowoff = (long long)row * Gd; } }
      } else {
        if (tile == 0){ int row = (c < 8) ? (gw + c) : (Gd + gw + c - 8);
                        src = w_ih; rowoff = (long long)row * Cd; }
        else { if (c < 8){ int row = 2*Gd + gw + c; src = w_ih; rowoff = (long long)row * Cd; }
               else zero = true; }
      }
      short8 shi, slo;
      #pragma unroll
      for (int j = 0; j < 8; j++){
        float v = zero ? 0.f : src[rowoff + kb + q*8 + j];
        unsigned short h = f2bf(v);
        unsigned short l = f2bf(v - bf2f(h));
        shi[j] = (short)h; slo[j] = (short)l;
      }
      wf[kt][tile][0] = shi; wf[kt][tile][1] = slo;
    }
  }

  // ---- Per-lane biases for the combine (indexed by acc row = 4q+i) ----
  float brz[4], bA[4], bB[4];
  #pragma unroll
  for (int i = 0; i < 4; i++){
    int row = 4*q + i;
    if (q < 2){ int idx = gw + row;  brz[i] = b_ih[idx] + b_hh[idx];
                int nr = 2*Gd + gw + row; bA[i] = b_ih[nr]; bB[i] = b_hh[nr]; }
    else      { int idx = Gd + gw + row - 8; brz[i] = b_ih[idx] + b_hh[idx];
                bA[i] = b_post[gw + row - 8]; bB[i] = 0.f; }
  }

  unsigned short* hhi_[2] = { h0hi, h1hi };
  unsigned short* hlo_[2] = { h0lo, h1lo };
  const f32x4 zero4 = {0.f, 0.f, 0.f, 0.f};

  for (int t = 0; t < Td; t++){
    // ---- parity barrier: pipelined single-line epoch poll (one lane) ----
    if (t > 0){
      if (tid == 0) poll_epoch(epoch, NPAR * t);
      __syncthreads();                                   // B1
    }

    const unsigned short* phi = hhi_[t & 1];
    const unsigned short* plo = hlo_[t & 1];
    unsigned short* nhi = hhi_[(t + 1) & 1];
    unsigned short* nlo = hlo_[(t + 1) & 1];

    // ---- Stage this WG's h slice [b0..b0+16) x [0..896) into LDS ----
    // Lane-contiguous 8B loads; LDS writes row-linear (conflict-free, R2).
    {
      const unsigned short* s_h = phi + (long long)b0 * Gd;
      const unsigned short* s_l = plo + (long long)b0 * Gd;
      unsigned long long vh[14], vl[14];
      #pragma unroll
      for (int j = 0; j < 14; j++){
        const int e8 = tid + j * 256;                    // u64 index 0..3583
        vh[j] = ald8u(s_h + e8 * 4);
        vl[j] = ald8u(s_l + e8 * 4);
      }
      #pragma unroll
      for (int j = 0; j < 14; j++){
        const int e8 = tid + j * 256;
        const int bl = e8 / 224;                         // batch row 0..15
        const int kk = (e8 - bl * 224) * 4;              // k offset 0..892
        *(unsigned long long*)(&sh_hi[bl * 904 + kk]) = vh[j];
        *(unsigned long long*)(&sh_lo[bl * 904 + kk]) = vl[j];
      }
    }
    __syncthreads();                                     // B2: slice visible

    // ---- B fragments from LDS (+ x plain loads for khi waves) ----
    short8 bh[16], bl_[16];
    if (!khi){
      #pragma unroll
      for (int kt = 0; kt < 16; kt++){
        bh[kt]  = *(const short8*)(&sh_hi[c * 904 + kt*32 + q*8]);
        bl_[kt] = *(const short8*)(&sh_lo[c * 904 + kt*32 + q*8]);
      }
    } else {
      #pragma unroll
      for (int kt = 0; kt < 12; kt++){
        bh[kt]  = *(const short8*)(&sh_hi[c * 904 + 512 + kt*32 + q*8]);
        bl_[kt] = *(const short8*)(&sh_lo[c * 904 + 512 + kt*32 + q*8]);
      }
      const long long xoff = ((long long)b * Td + t) * Cd;
      #pragma unroll
      for (int kt = 12; kt < 16; kt++){  // x: plain loads, L2-cached
        bh[kt]  = *(const short8*)(xhi + xoff + (kt - 12)*32 + q*8);
        bl_[kt] = *(const short8*)(xlo + xoff + (kt - 12)*32 + q*8);
      }
    }
    us4 hpH, hpL;                        // h_prev slice for the update (khi, q<2)
    if (khi && q < 2){
      hpH = *(const us4*)(&sh_hi[c * 904 + gw + 4*q]);
      hpL = *(const us4*)(&sh_lo[c * 904 + gw + 4*q]);
    }

    // ---- MFMA K-loop: main + two correction chains per tile ----
    f32x4 a0m = zero4, a0c = zero4, a0d = zero4;
    f32x4 a1m = zero4, a1c = zero4, a1d = zero4;
    f32x4 axm = zero4, axc = zero4, axd = zero4;
    #pragma unroll
    for (int kt = 0; kt < 16; kt++){
      const bool isx = khi && (kt >= 12);
      const short8 w0h = wf[kt][0][0], w0l = wf[kt][0][1];
      const short8 w1h = wf[kt][1][0], w1l = wf[kt][1][1];
      a0m = mfma16(w0h, bh[kt], a0m);
      a0c = mfma16(w0h, bl_[kt], a0c);
      a0d = mfma16(w0l, bh[kt], a0d);
      if (!isx){
        a1m = mfma16(w1h, bh[kt], a1m);
        a1c = mfma16(w1h, bl_[kt], a1c);
        a1d = mfma16(w1l, bh[kt], a1d);
      } else {
        axm = mfma16(w1h, bh[kt], axm);
        axc = mfma16(w1h, bl_[kt], axc);
        axd = mfma16(w1l, bh[kt], axd);
      }
    }

    f32x4 sT0 = (a0m + a0c) + a0d;
    f32x4 sT1 = (a1m + a1c) + a1d;
    if (!khi){
      #pragma unroll
      for (int i = 0; i < 4; i++){ lred[cw][lane][i] = sT0[i]; lred[cw][lane][4+i] = sT1[i]; }
    }
    __syncthreads();                                     // B3

    if (khi){
      #pragma unroll
      for (int i = 0; i < 4; i++){ sT0[i] += lred[cw][lane][i]; sT1[i] += lred[cw][lane][4+i]; }
      f32x4 sX = (axm + axc) + axd;

      // sigmoid of T0 rows: q<2 -> r values, q>=2 -> z values
      float sv[4];
      #pragma unroll
      for (int i = 0; i < 4; i++) sv[i] = 1.f / (1.f + __expf(-(sT0[i] + brz[i])));
      float zv[4];
      #pragma unroll
      for (int i = 0; i < 4; i++) zv[i] = __shfl_down(sv[i], 32);

      if (q < 2){
        us4 sh, sl; f32x4 hf;
        #pragma unroll
        for (int i = 0; i < 4; i++){
          float hp = bf2f(hpH[i]) + bf2f(hpL[i]);
          float n  = tanhf((sX[i] + bA[i]) + sv[i] * (sT1[i] + bB[i]));
          float hv = (1.f - zv[i]) * n + zv[i] * hp;
          hf[i] = hv;
          unsigned short hh = f2bf(hv);
          sh[i] = hh; sl[i] = f2bf(hv - bf2f(hh));
        }
        ast8(nhi + (long long)b * Gd + gw + 4*q, sh);   // publish h gen t+1
        ast8(nlo + (long long)b * Gd + gw + 4*q, sl);
        if (t == Td - 1)
          *(f32x4*)(hlast + (long long)b * Gd + gw + 4*q) = hf;
      } else {
        if (t > 0){
          f32x4 o;
          #pragma unroll
          for (int i = 0; i < 4; i++){ float v = sT1[i] + bA[i]; o[i] = v > 0.f ? v : 0.f; }
          *(f32x4*)(out + ((long long)b * Td + (t - 1)) * HDd + gw + 4*(q - 2)) = o;
        }
      }
    }
    // __syncthreads() drains each wave's vmcnt (h stores MALL-visible)
    __syncthreads();                                     // B4
    if (tid == 0){
      __builtin_amdgcn_s_waitcnt(0);     // belt & braces: own wave's stores drained
      __hip_atomic_fetch_add(epoch, 1, __ATOMIC_RELAXED, __HIP_MEMORY_SCOPE_AGENT);
    }
  }

  // ---- Epilogue: out[:, T-1, :] = relu(w_post . h_T + b) ----
  if (tid == 0) poll_epoch(epoch, NPAR * Td);
  __syncthreads();

  const unsigned short* fhi = hhi_[Td & 1] + (long long)b * Gd;   // = h0 planes
  const unsigned short* flo = hlo_[Td & 1] + (long long)b * Gd;
  f32x4 apm = zero4, apc = zero4, apd = zero4;
  const int nkt = khi ? 12 : 16;
  #pragma unroll
  for (int kt = 0; kt < 16; kt++){
    if (kt < nkt){
      const int off = khi ? (512 + kt*32 + q*8) : (kt*32 + q*8);
      short8 vh = ald16(fhi + off);
      short8 vl = ald16(flo + off);
      apm = mfma16(wf[kt][1][0], vh, apm);
      apc = mfma16(wf[kt][1][0], vl, apc);
      apd = mfma16(wf[kt][1][1], vh, apd);
    }
  }
  f32x4 sP = (apm + apc) + apd;
  if (!khi){
    #pragma unroll
    for (int i = 0; i < 4; i++) lred[cw][lane][i] = sP[i];
  }
  __syncthreads();
  if (khi && q >= 2){
    #pragma unroll
    for (int i = 0; i < 4; i++) sP[i] += lred[cw][lane][i];
    f32x4 o;
    #pragma unroll
    for (int i = 0; i < 4; i++){ float v = sP[i] + bA[i]; o[i] = v > 0.f ? v : 0.f; }
    *(f32x4*)(out + ((long long)b * Td + (Td - 1)) * HDd + gw + 4*(q - 2)) = o;
  }
}

// ---------------------------------------------------------------------------
extern "C" void kernel_launch(void* const* d_in, const int* in_sizes, int n_in,
                              void* d_out, int out_size, void* d_ws, size_t ws_size,
                              hipStream_t stream)
{
  const float* x      = (const float*)d_in[0];
  const float* state  = (const float*)d_in[1];
  const float* w_ih   = (const float*)d_in[2];
  const float* w_hh   = (const float*)d_in[3];
  const float* b_ih   = (const float*)d_in[4];
  const float* b_hh   = (const float*)d_in[5];
  const float* w_post = (const float*)d_in[6];
  const float* b_post = (const float*)d_in[7];

  float* out   = (float*)d_out;
  float* hlast = out + (long long)Bd * Td * HDd;

  // workspace layout (~17.0 MB)
  char* ws = (char*)d_ws;
  unsigned short* xhi  = (unsigned short*)ws;                      //  8,388,608 B
  unsigned short* xlo  = (unsigned short*)(ws +  8388608);         //  8,388,608 B
  unsigned short* h0hi = (unsigned short*)(ws + 16777216);         //     57,344 B
  unsigned short* h0lo = (unsigned short*)(ws + 16834560);         //     57,344 B
  unsigned short* h1hi = (unsigned short*)(ws + 16891904);         //     57,344 B
  unsigned short* h1lo = (unsigned short*)(ws + 16949248);         //     57,344 B
  int*            ctrl = (int*)(ws + 17006592);                    //      2,048 B

  hipLaunchKernelGGL(init_k, dim3(2048), dim3(256), 0, stream,
                     x, state, xhi, xlo, h0hi, h0lo, ctrl);

  hipLaunchKernelGGL(gru_persistent, dim3(NWG), dim3(256), 0, stream,
                     w_ih, w_hh, b_ih, b_hh, w_post, b_post, xhi, xlo,
                     h0hi, h0lo, h1hi, h1lo, ctrl, out, hlast);
}